// Round 5
// baseline (1050.822 us; speedup 1.0000x reference)
//
#include <hip/hip_runtime.h>

#define BB 16
#define NN 8192
#define SS 512
#define N3 (3 * NN)  // 24576 elements per batch per tensor
#define KD 14        // per-lane KNN list depth (see knn comment)
#define KNN_BLOCKS 128
#define KNN_WAVES (KNN_BLOCKS * 8)

typedef unsigned short u16;
typedef unsigned int u32;
typedef unsigned long long u64;
typedef float v2f __attribute__((ext_vector_type(2)));

// Packed fp32 ops (VOP3P, 2 points/inst). Per-half rounding is IEEE rn —
// bit-identical to scalar __fadd_rn/__fmul_rn.
__device__ __forceinline__ v2f pk_add(v2f a, v2f b) {
  v2f r;
  asm("v_pk_add_f32 %0, %1, %2" : "=v"(r) : "v"(a), "v"(b));
  return r;
}
__device__ __forceinline__ v2f pk_mul(v2f a, v2f b) {
  v2f r;
  asm("v_pk_mul_f32 %0, %1, %2" : "=v"(r) : "v"(a), "v"(b));
  return r;
}

// u64 max step over a DPP lane-shift: shift both 32-bit halves with the same
// control (old=0 is the identity for max of our non-negative keys), then one
// v_cmp_lt_u64 + 2 cndmask. Stays entirely on the VALU pipe — r15's lesson:
// __shfl_xor is ds_bpermute (LDS pipe, ~40+cy dependent) and 9 such steps on
// the serial path cost ~+500cy/iter (544 -> 658 us).
template <int CTRL>
__device__ __forceinline__ u64 dpp_maxk(u64 k) {
  u32 lo = (u32)k, hi = (u32)(k >> 32);
  u32 slo = (u32)__builtin_amdgcn_update_dpp(0, (int)lo, CTRL, 0xf, 0xf, false);
  u32 shi = (u32)__builtin_amdgcn_update_dpp(0, (int)hi, CTRL, 0xf, 0xf, false);
  u64 s = ((u64)shi << 32) | (u64)slo;
  return (s > k) ? s : k;
}
__device__ __forceinline__ u64 maxk(u64 a, u64 b) { return (a > b) ? a : b; }

// ---------------------------------------------------------------------------
// K0: precompute per-point float4 {x,y,z,|q|^2} for xyz and {x,y,z,0} for
// l0_points into workspace (|q|^2 uses the EXACT rn tree -> bits unchanged
// downstream). Also zeroes the 16 per-batch progress flags each replay
// (graph replays reuse workspace; stream order puts this before the mega
// kernel).
// ---------------------------------------------------------------------------
__global__ __launch_bounds__(256) void k_prep(const float* __restrict__ xyz,
                                              const float* __restrict__ pts,
                                              float4* __restrict__ xyz4,
                                              float4* __restrict__ pts4,
                                              u32* __restrict__ progress) {
  if (blockIdx.x == 0 && threadIdx.x < BB)
    __hip_atomic_store(progress + threadIdx.x, 0u, __ATOMIC_RELAXED,
                       __HIP_MEMORY_SCOPE_AGENT);
  int i = blockIdx.x * 256 + threadIdx.x;  // < BB*NN
  int b = i >> 13, n = i & (NN - 1);
  const float* xb = xyz + b * N3;
  float x = xb[n], y = xb[NN + n], z = xb[2 * NN + n];
  float w = __fadd_rn(__fadd_rn(__fmul_rn(x, x), __fmul_rn(y, y)), __fmul_rn(z, z));
  xyz4[i] = make_float4(x, y, z, w);
  const float* pb = pts + b * N3;
  pts4[i] = make_float4(pb[n], pb[NN + n], pb[2 * NN + n], 0.f);
}

// ---------------------------------------------------------------------------
// K1 (r18): FPS + KNN fused in ONE kernel, overlapped via intra-kernel
// producer/consumer flags. k_fps only uses 16 CUs; 240 idle for 506us. The
// KNN row (b,s) needs ONLY keypoint s of batch b, and keypoint #it IS the
// FPS center at iteration it (carry-before-update scan). So FPS blocks
// (blockIdx 0..15) publish each keypoint as they go; KNN blocks (16..143,
// 1024 waves, 8 rows/wave, s-major order) consume them concurrently.
//
// Coherence (per-XCD L2 NOT cross-coherent): coords + progress go through
// agent-scope atomics (coherence-point stores/loads). Flag for keypoint it-1
// is published at iter it AFTER s_waitcnt vmcnt(0) — those coord stores were
// issued a full iteration (~2300cy) earlier, so the wait is free, and the
// waitcnt guarantees store->flag order. Consumers spin on lane0 (s_sleep),
// then a compiler memory barrier before the coord loads (atomic loads bypass
// stale L2 by construction).
//
// Deadlock-free by residency: 144 blocks x ~100KB LDS = 1 block/CU <= 256
// CUs -> the whole grid is co-resident regardless of dispatch order.
//
// FPS core is r16's, UNCHANGED (bit-exact vs numpy: see r16 notes — vmax
// bit-equality find, key = dist<<32 | NN-idx, DPP-only cross-lane, one
// barrier/iter). KNN core is r17's float4 path, coords now from atomic kp
// loads (bit-identical values).
// ---------------------------------------------------------------------------
__global__ __attribute__((amdgpu_flat_work_group_size(512, 512),
                          amdgpu_waves_per_eu(2, 2)))
void k_fps_knn(const float* __restrict__ xyz, const float4* __restrict__ xyz4,
               float* __restrict__ out_kp, u16* __restrict__ knn,
               u32* __restrict__ progress) {
  __shared__ float sxyz[NN * 3];  // [idx][x,y,z] (FPS blocks only)
  __shared__ u64 rkey[2][8];
  int t = threadIdx.x;
  int lane = t & 63, w = t >> 6;
  if (blockIdx.x < BB) {
    // ---------------- FPS producer ----------------
    int b = blockIdx.x;
    const float* base = xyz + b * N3;
    v2f px[8], py[8], pz[8], dm[8];
#pragma unroll
    for (int j = 0; j < 8; ++j) {
      int n0 = j * 1024 + t, n1 = n0 + 512;  // coalesced, disjoint cover
      px[j] = v2f{base[n0], base[n1]};
      py[j] = v2f{base[NN + n0], base[NN + n1]};
      pz[j] = v2f{base[2 * NN + n0], base[2 * NN + n1]};
      dm[j] = v2f{1e10f, 1e10f};
      sxyz[n0 * 3 + 0] = px[j].x;  // stage AoS copy for center re-loads
      sxyz[n0 * 3 + 1] = py[j].x;
      sxyz[n0 * 3 + 2] = pz[j].x;
      sxyz[n1 * 3 + 0] = px[j].y;
      sxyz[n1 * 3 + 1] = py[j].y;
      sxyz[n1 * 3 + 2] = pz[j].y;
    }
#pragma unroll
    for (int j = 0; j < 8; ++j) {
      // Opaque def: blocks rematerialization of the global loads.
      asm volatile("" : "+v"(px[j]), "+v"(py[j]), "+v"(pz[j]));
    }
    float cx = base[0], cy = base[NN], cz = base[2 * NN];
    u32 tb = (u32)(NN - t);  // cand = NN - gidx (1..8192; 0=none)
    for (int it = 0; it < SS; ++it) {
      // publish: flag keypoint it-1 (its stores drained — issued last iter),
      // then issue keypoint it's coord stores (= current center, exact LDS
      // copies of base). Compiler barrier keeps waitcnt->flag order.
      if (t == 0) {
        if (it > 0) {
          asm volatile("s_waitcnt vmcnt(0)" ::: "memory");
          __hip_atomic_store(progress + b, (u32)it, __ATOMIC_RELAXED,
                             __HIP_MEMORY_SCOPE_AGENT);
        }
        __hip_atomic_store(out_kp + b * 1536 + it, cx, __ATOMIC_RELAXED,
                           __HIP_MEMORY_SCOPE_AGENT);
        __hip_atomic_store(out_kp + b * 1536 + SS + it, cy, __ATOMIC_RELAXED,
                           __HIP_MEMORY_SCOPE_AGENT);
        __hip_atomic_store(out_kp + b * 1536 + 2 * SS + it, cz, __ATOMIC_RELAXED,
                           __HIP_MEMORY_SCOPE_AGENT);
      }
      // negated center, broadcast to both halves (a + (-c) == a - c exactly)
      v2f ncx = v2f{-cx, -cx}, ncy = v2f{-cy, -cy}, ncz = v2f{-cz, -cz};
      float vmax = 0.0f;
#pragma unroll
      for (int j = 0; j < 8; ++j) {
        v2f dx = pk_add(px[j], ncx);
        v2f dy = pk_add(py[j], ncy);
        v2f dz = pk_add(pz[j], ncz);
        v2f xx = pk_mul(dx, dx);
        v2f yy = pk_mul(dy, dy);
        v2f s = pk_add(xx, yy);
        v2f zz = pk_mul(dz, dz);
        v2f d = pk_add(s, zz);  // ((dx^2+dy^2)+dz^2), numpy tree per half
        float a0 = fminf(dm[j].x, d.x);
        float a1 = fminf(dm[j].y, d.y);
        dm[j].x = a0;
        dm[j].y = a1;
        vmax = fmaxf(vmax, fmaxf(a0, a1));  // max3-foldable
      }
      // thread-local find vs OWN max: exact bit-equality (vmax IS one of this
      // thread's dm values). Descending gidx -> LAST write = lowest gidx.
      u32 cand = 0;
#pragma unroll
      for (int j = 7; j >= 0; --j) {
        u32 v1 = tb - (u32)(j * 1024 + 512);  // .y half (higher gidx)
        u32 v0 = tb - (u32)(j * 1024);        // .x half
        cand = (dm[j].y == vmax) ? v1 : cand;
        cand = (dm[j].x == vmax) ? v0 : cand;
      }
      // 6-step DPP u64 max chain -> lane63 = wave best. VALU pipe only.
      u64 key = ((u64)__float_as_uint(vmax) << 32) | cand;
      key = dpp_maxk<0x111>(key);  // row_shr:1
      key = dpp_maxk<0x112>(key);  // row_shr:2
      key = dpp_maxk<0x114>(key);  // row_shr:4
      key = dpp_maxk<0x118>(key);  // row_shr:8
      key = dpp_maxk<0x142>(key);  // row_bcast:15
      key = dpp_maxk<0x143>(key);  // row_bcast:31
      int pb = it & 1;  // parity double-buffer: safe with one barrier/iter
      if (lane == 63) rkey[pb][w] = key;
      __syncthreads();  // the only barrier per iteration
      // block reduce: every thread broadcast-reads all 8 wave keys + redundant
      // VALU tree (no cross-lane ops in this phase).
      u64 k0 = rkey[pb][0], k1 = rkey[pb][1];
      u64 k2 = rkey[pb][2], k3 = rkey[pb][3];
      u64 k4 = rkey[pb][4], k5 = rkey[pb][5];
      u64 k6 = rkey[pb][6], k7 = rkey[pb][7];
      u64 kg = maxk(maxk(maxk(k0, k1), maxk(k2, k3)),
                    maxk(maxk(k4, k5), maxk(k6, k7)));
      int far = NN - (int)(u32)(kg & 0xffffffffu);
      // broadcast ds_read of the winner's coords (all lanes same address)
      cx = sxyz[far * 3 + 0];
      cy = sxyz[far * 3 + 1];
      cz = sxyz[far * 3 + 2];
    }
    // final keypoint (#511) was stored inside iter 511; drain + final flag
    if (t == 0) {
      asm volatile("s_waitcnt vmcnt(0)" ::: "memory");
      __hip_atomic_store(progress + b, (u32)SS, __ATOMIC_RELAXED,
                         __HIP_MEMORY_SCOPE_AGENT);
    }
  } else {
    // ---------------- KNN consumer ----------------
    // 1024 waves x 8 passes = 8192 rows, s-major (wid = s*16 + b) so each
    // wave's rows become available in the order it visits them.
    int wg = (blockIdx.x - BB) * 8 + w;
    for (int pass = 0; pass < 8; ++pass) {
      int wid = wg + pass * KNN_WAVES;
      int s = wid >> 4, b = wid & 15;
      if (lane == 0) {
        while (__hip_atomic_load(progress + b, __ATOMIC_ACQUIRE,
                                 __HIP_MEMORY_SCOPE_AGENT) <= (u32)s)
          __builtin_amdgcn_s_sleep(2);
      }
      asm volatile("" ::: "memory");  // no hoisting loads above the spin
      float ax = __hip_atomic_load(out_kp + b * 1536 + s, __ATOMIC_RELAXED,
                                   __HIP_MEMORY_SCOPE_AGENT);
      float ay = __hip_atomic_load(out_kp + b * 1536 + SS + s, __ATOMIC_RELAXED,
                                   __HIP_MEMORY_SCOPE_AGENT);
      float az = __hip_atomic_load(out_kp + b * 1536 + 2 * SS + s, __ATOMIC_RELAXED,
                                   __HIP_MEMORY_SCOPE_AGENT);
      float aw = __fadd_rn(__fadd_rn(__fmul_rn(ax, ax), __fmul_rn(ay, ay)),
                           __fmul_rn(az, az));
      const float4* base4 = xyz4 + (b << 13);
      u64 arr[KD];
#pragma unroll
      for (int i = 0; i < KD; ++i) arr[i] = ~0ull;
      for (int c = 0; c < 128; ++c) {
        int n = c * 64 + lane;
        float4 q = base4[n];  // one dwordx4, coalesced
        float dot = __fadd_rn(__fadd_rn(__fmul_rn(ax, q.x), __fmul_rn(ay, q.y)),
                              __fmul_rn(az, q.z));
        float d = __fsub_rn(__fadd_rn(aw, q.w), __fmul_rn(2.0f, dot));
        u32 ub = __float_as_uint(d);
        ub ^= (ub & 0x80000000u) ? 0xFFFFFFFFu : 0x80000000u;  // order-preserving
        u64 key = ((u64)ub << 32) | (u32)n;
        if (key < arr[KD - 1]) {  // sorted insert, CSE'd conditions
          bool cg[KD];
#pragma unroll
          for (int i = 0; i < KD; ++i) cg[i] = arr[i] > key;
#pragma unroll
          for (int i = KD - 1; i >= 1; --i)
            arr[i] = cg[i - 1] ? arr[i - 1] : (cg[i] ? key : arr[i]);
          arr[0] = cg[0] ? key : arr[0];
        }
      }
      // merge 64 sorted lists: 24 x (wave-min of heads, winner pops).
      u64 mine = 0;
      for (int it = 0; it < 24; ++it) {
        u64 m = arr[0];
#pragma unroll
        for (int off = 1; off < 64; off <<= 1) {
          u64 o = __shfl_xor(m, off, 64);
          m = (o < m) ? o : m;
        }
        if (lane == it) mine = m;
        if (arr[0] == m) {
#pragma unroll
          for (int i = 0; i < KD - 1; ++i) arr[i] = arr[i + 1];
          arr[KD - 1] = ~0ull;
        }
      }
      int row = b * SS + s;
      if (lane < 24) knn[row * 24 + lane] = (u16)(mine & 0xFFFFu);
    }
  }
}

// ---------------------------------------------------------------------------
// Fallback solo kernels (workspace too small for float4/flags): r16 k_fps +
// r17 k_knn scalar path, serial. Not used when ws suffices.
// ---------------------------------------------------------------------------
__global__ __attribute__((amdgpu_flat_work_group_size(512, 512),
                          amdgpu_waves_per_eu(2, 2)))
void k_fps_solo(const float* __restrict__ xyz, float* __restrict__ out_kp) {
  __shared__ float sxyz[NN * 3];
  __shared__ int sIdx[SS];
  __shared__ u64 rkey[2][8];
  int b = blockIdx.x, t = threadIdx.x;
  const float* base = xyz + b * N3;
  v2f px[8], py[8], pz[8], dm[8];
#pragma unroll
  for (int j = 0; j < 8; ++j) {
    int n0 = j * 1024 + t, n1 = n0 + 512;
    px[j] = v2f{base[n0], base[n1]};
    py[j] = v2f{base[NN + n0], base[NN + n1]};
    pz[j] = v2f{base[2 * NN + n0], base[2 * NN + n1]};
    dm[j] = v2f{1e10f, 1e10f};
    sxyz[n0 * 3 + 0] = px[j].x;
    sxyz[n0 * 3 + 1] = py[j].x;
    sxyz[n0 * 3 + 2] = pz[j].x;
    sxyz[n1 * 3 + 0] = px[j].y;
    sxyz[n1 * 3 + 1] = py[j].y;
    sxyz[n1 * 3 + 2] = pz[j].y;
  }
#pragma unroll
  for (int j = 0; j < 8; ++j) asm volatile("" : "+v"(px[j]), "+v"(py[j]), "+v"(pz[j]));
  float cx = base[0], cy = base[NN], cz = base[2 * NN];
  int far = 0;
  int lane = t & 63, w = t >> 6;
  u32 tb = (u32)(NN - t);
  for (int it = 0; it < SS; ++it) {
    if (t == 0) sIdx[it] = far;
    v2f ncx = v2f{-cx, -cx}, ncy = v2f{-cy, -cy}, ncz = v2f{-cz, -cz};
    float vmax = 0.0f;
#pragma unroll
    for (int j = 0; j < 8; ++j) {
      v2f dx = pk_add(px[j], ncx);
      v2f dy = pk_add(py[j], ncy);
      v2f dz = pk_add(pz[j], ncz);
      v2f xx = pk_mul(dx, dx);
      v2f yy = pk_mul(dy, dy);
      v2f s = pk_add(xx, yy);
      v2f zz = pk_mul(dz, dz);
      v2f d = pk_add(s, zz);
      float a0 = fminf(dm[j].x, d.x);
      float a1 = fminf(dm[j].y, d.y);
      dm[j].x = a0;
      dm[j].y = a1;
      vmax = fmaxf(vmax, fmaxf(a0, a1));
    }
    u32 cand = 0;
#pragma unroll
    for (int j = 7; j >= 0; --j) {
      u32 v1 = tb - (u32)(j * 1024 + 512);
      u32 v0 = tb - (u32)(j * 1024);
      cand = (dm[j].y == vmax) ? v1 : cand;
      cand = (dm[j].x == vmax) ? v0 : cand;
    }
    u64 key = ((u64)__float_as_uint(vmax) << 32) | cand;
    key = dpp_maxk<0x111>(key);
    key = dpp_maxk<0x112>(key);
    key = dpp_maxk<0x114>(key);
    key = dpp_maxk<0x118>(key);
    key = dpp_maxk<0x142>(key);
    key = dpp_maxk<0x143>(key);
    int pb = it & 1;
    if (lane == 63) rkey[pb][w] = key;
    __syncthreads();
    u64 k0 = rkey[pb][0], k1 = rkey[pb][1];
    u64 k2 = rkey[pb][2], k3 = rkey[pb][3];
    u64 k4 = rkey[pb][4], k5 = rkey[pb][5];
    u64 k6 = rkey[pb][6], k7 = rkey[pb][7];
    u64 kg = maxk(maxk(maxk(k0, k1), maxk(k2, k3)),
                  maxk(maxk(k4, k5), maxk(k6, k7)));
    far = NN - (int)(u32)(kg & 0xffffffffu);
    cx = sxyz[far * 3 + 0];
    cy = sxyz[far * 3 + 1];
    cz = sxyz[far * 3 + 2];
  }
  __syncthreads();
  for (int i = t; i < SS; i += 512) {
    int id = sIdx[i];
    out_kp[b * 1536 + i] = base[id];
    out_kp[b * 1536 + SS + i] = base[NN + id];
    out_kp[b * 1536 + 2 * SS + i] = base[2 * NN + id];
  }
}

__global__ __launch_bounds__(256) void k_knn_solo(const float* __restrict__ xyz,
                                                  const float* __restrict__ kp,
                                                  u16* __restrict__ knn) {
  int t = threadIdx.x;
  int row = blockIdx.x * 4 + (t >> 6);
  int lane = t & 63;
  int b = row >> 9, s = row & (SS - 1);
  const float* base = xyz + b * N3;
  float ax = kp[b * 1536 + s];
  float ay = kp[b * 1536 + SS + s];
  float az = kp[b * 1536 + 2 * SS + s];
  float aw = __fadd_rn(__fadd_rn(__fmul_rn(ax, ax), __fmul_rn(ay, ay)), __fmul_rn(az, az));
  u64 arr[KD];
#pragma unroll
  for (int i = 0; i < KD; ++i) arr[i] = ~0ull;
  for (int c = 0; c < 128; ++c) {
    int n = c * 64 + lane;
    float qx = base[n], qy = base[NN + n], qz = base[2 * NN + n];
    float qw = __fadd_rn(__fadd_rn(__fmul_rn(qx, qx), __fmul_rn(qy, qy)), __fmul_rn(qz, qz));
    float dot = __fadd_rn(__fadd_rn(__fmul_rn(ax, qx), __fmul_rn(ay, qy)), __fmul_rn(az, qz));
    float d = __fsub_rn(__fadd_rn(aw, qw), __fmul_rn(2.0f, dot));
    u32 ub = __float_as_uint(d);
    ub ^= (ub & 0x80000000u) ? 0xFFFFFFFFu : 0x80000000u;
    u64 key = ((u64)ub << 32) | (u32)n;
    if (key < arr[KD - 1]) {
      bool cg[KD];
#pragma unroll
      for (int i = 0; i < KD; ++i) cg[i] = arr[i] > key;
#pragma unroll
      for (int i = KD - 1; i >= 1; --i)
        arr[i] = cg[i - 1] ? arr[i - 1] : (cg[i] ? key : arr[i]);
      arr[0] = cg[0] ? key : arr[0];
    }
  }
  u64 mine = 0;
  for (int it = 0; it < 24; ++it) {
    u64 m = arr[0];
#pragma unroll
    for (int off = 1; off < 64; off <<= 1) {
      u64 o = __shfl_xor(m, off, 64);
      m = (o < m) ? o : m;
    }
    if (lane == it) mine = m;
    if (arr[0] == m) {
#pragma unroll
      for (int i = 0; i < KD - 1; ++i) arr[i] = arr[i + 1];
      arr[KD - 1] = ~0ull;
    }
  }
  if (lane < 24) knn[row * 24 + lane] = (u16)(mine & 0xFFFFu);
}

// ---------------------------------------------------------------------------
// K3 (r17, unchanged): fused base-SA + multi-scale MLPs. blockIdx.y = 0 ->
// base (feat [rel_xyz|pts] 6->64 relu -> 64->128, K=16, out ch 0..127);
// blockIdx.y = 1..3 -> ms scale y-1 (rel_xyz 3->64 relu -> 64->128, K=8y,
// out ch 128y..128y+127). Branch is block-uniform. Staging gathers via
// float4 (USE4). Per-wave h2: thread owns 2 out channels, W2 rows in
// registers, h1 read as wave-uniform float4 broadcast.
// ---------------------------------------------------------------------------
template <int USE4>
__global__ __launch_bounds__(256) void k_mlp(
    const float* __restrict__ xyz, const float* __restrict__ pts,
    const float4* __restrict__ xyz4, const float4* __restrict__ pts4,
    const float* __restrict__ kp, const u16* __restrict__ knn,
    const float* __restrict__ W1, const float* __restrict__ b1,
    const float* __restrict__ W2, const float* __restrict__ b2,
    const float* __restrict__ msW1, const float* __restrict__ msb1,
    const float* __restrict__ msW2, const float* __restrict__ msb2,
    float* __restrict__ out) {
  __shared__ float smem[6688];
  int t = threadIdx.x, lane = t & 63, w = t >> 6;
  int b = blockIdx.x >> 6, s0 = (blockIdx.x & 63) * 8;
  if (blockIdx.y == 0) {
    float* sW1T = smem;
    float* sb1 = smem + 384;
    float* sfeat = smem + 448;
    float* sh1 = smem + 832;
    for (int i = t; i < 384; i += 256) {
      int o = i / 6, c = i - o * 6;
      sW1T[c * 64 + o] = W1[i];
    }
    if (t < 64) sb1[t] = b1[t];
    float wgtA[64], wgtB[64];
#pragma unroll
    for (int j = 0; j < 64; ++j) {
      wgtA[j] = W2[lane * 64 + j];
      wgtB[j] = W2[(lane + 64) * 64 + j];
    }
    float b2A = b2[lane], b2B = b2[lane + 64];
    __syncthreads();
    for (int g = 0; g < 2; ++g) {
      if (t < 128) {  // 64 (rr,k) pairs x 2 halves: h=0 xyz, h=1 pts
        int p = t >> 1, h = t & 1;
        int rr = p >> 4, k = p & 15;
        int s = s0 + g * 4 + rr, row = b * SS + s;
        int id = knn[row * 24 + k];
        float* f = &sfeat[rr * 96 + k * 6];
        if (h == 0) {
          float qx, qy, qz;
          if constexpr (USE4) {
            float4 q = xyz4[(b << 13) + id];
            qx = q.x; qy = q.y; qz = q.z;
          } else {
            qx = xyz[b * N3 + id];
            qy = xyz[b * N3 + NN + id];
            qz = xyz[b * N3 + 2 * NN + id];
          }
          f[0] = __fsub_rn(qx, kp[b * 1536 + s]);
          f[1] = __fsub_rn(qy, kp[b * 1536 + SS + s]);
          f[2] = __fsub_rn(qz, kp[b * 1536 + 2 * SS + s]);
        } else {
          float px_, py_, pz_;
          if constexpr (USE4) {
            float4 q = pts4[(b << 13) + id];
            px_ = q.x; py_ = q.y; pz_ = q.z;
          } else {
            px_ = pts[b * N3 + id];
            py_ = pts[b * N3 + NN + id];
            pz_ = pts[b * N3 + 2 * NN + id];
          }
          f[3] = px_;
          f[4] = py_;
          f[5] = pz_;
        }
      }
      __syncthreads();
#pragma unroll
      for (int m = 0; m < 16; ++m) {
        int u = m * 256 + t;
        int rr = u >> 10, rem = u & 1023, k = rem >> 6, o = rem & 63;
        float acc = sb1[o];
#pragma unroll
        for (int c = 0; c < 6; ++c) acc = fmaf(sfeat[rr * 96 + k * 6 + c], sW1T[c * 64 + o], acc);
        sh1[rr * 1024 + k * 64 + o] = fmaxf(acc, 0.f);
      }
      __syncthreads();
      float bestA = -1e30f, bestB = -1e30f;
#pragma unroll
      for (int k = 0; k < 16; ++k) {
        const float4* h4 = (const float4*)&sh1[w * 1024 + k * 64];
        float a0 = 0.f, a1 = 0.f;
#pragma unroll
        for (int j = 0; j < 16; ++j) {
          float4 hv = h4[j];
          a0 = fmaf(hv.x, wgtA[4 * j], a0);
          a0 = fmaf(hv.y, wgtA[4 * j + 1], a0);
          a0 = fmaf(hv.z, wgtA[4 * j + 2], a0);
          a0 = fmaf(hv.w, wgtA[4 * j + 3], a0);
          a1 = fmaf(hv.x, wgtB[4 * j], a1);
          a1 = fmaf(hv.y, wgtB[4 * j + 1], a1);
          a1 = fmaf(hv.z, wgtB[4 * j + 2], a1);
          a1 = fmaf(hv.w, wgtB[4 * j + 3], a1);
        }
        bestA = fmaxf(bestA, a0);
        bestB = fmaxf(bestB, a1);
      }
      int s = s0 + g * 4 + w;
      out[24576 + b * 262144 + lane * 512 + s] = bestA + b2A;
      out[24576 + b * 262144 + (lane + 64) * 512 + s] = bestB + b2B;
      __syncthreads();
    }
  } else {
    int scale = blockIdx.y - 1;
    int kk = 8 * (scale + 1);
    float* sW1T = smem;
    float* sb1 = smem + 192;
    float* sfeat = smem + 256;
    float* sh1 = smem + 544;
    const float* W1s = msW1 + scale * 192;
    for (int i = t; i < 192; i += 256) {
      int o = i / 3, c = i - o * 3;
      sW1T[c * 64 + o] = W1s[i];
    }
    if (t < 64) sb1[t] = msb1[scale * 64 + t];
    float wgtA[64], wgtB[64];
#pragma unroll
    for (int j = 0; j < 64; ++j) {
      wgtA[j] = msW2[scale * 8192 + lane * 64 + j];
      wgtB[j] = msW2[scale * 8192 + (lane + 64) * 64 + j];
    }
    float b2A = msb2[scale * 128 + lane], b2B = msb2[scale * 128 + lane + 64];
    __syncthreads();
    int co = 128 * (scale + 1);
    for (int g = 0; g < 2; ++g) {
      if (t < 96) {  // 4 rows x 24 slots (stage all 24; h1 reads only k<kk)
        int rr = t / 24, k = t - rr * 24;
        int s = s0 + g * 4 + rr, row = b * SS + s;
        int id = knn[row * 24 + k];
        float qx, qy, qz;
        if constexpr (USE4) {
          float4 q = xyz4[(b << 13) + id];
          qx = q.x; qy = q.y; qz = q.z;
        } else {
          qx = xyz[b * N3 + id];
          qy = xyz[b * N3 + NN + id];
          qz = xyz[b * N3 + 2 * NN + id];
        }
        float* f = &sfeat[rr * 72 + k * 3];
        f[0] = __fsub_rn(qx, kp[b * 1536 + s]);
        f[1] = __fsub_rn(qy, kp[b * 1536 + SS + s]);
        f[2] = __fsub_rn(qz, kp[b * 1536 + 2 * SS + s]);
      }
      __syncthreads();
      for (int rr = 0; rr < 4; ++rr) {
        for (int u = t; u < kk * 64; u += 256) {
          int k = u >> 6, o = u & 63;
          float acc = sb1[o];
          acc = fmaf(sfeat[rr * 72 + k * 3 + 0], sW1T[o], acc);
          acc = fmaf(sfeat[rr * 72 + k * 3 + 1], sW1T[64 + o], acc);
          acc = fmaf(sfeat[rr * 72 + k * 3 + 2], sW1T[128 + o], acc);
          sh1[rr * 1536 + k * 64 + o] = fmaxf(acc, 0.f);
        }
      }
      __syncthreads();
      float bestA = -1e30f, bestB = -1e30f;
      for (int k = 0; k < kk; ++k) {
        const float4* h4 = (const float4*)&sh1[w * 1536 + k * 64];
        float a0 = 0.f, a1 = 0.f;
#pragma unroll
        for (int j = 0; j < 16; ++j) {
          float4 hv = h4[j];
          a0 = fmaf(hv.x, wgtA[4 * j], a0);
          a0 = fmaf(hv.y, wgtA[4 * j + 1], a0);
          a0 = fmaf(hv.z, wgtA[4 * j + 2], a0);
          a0 = fmaf(hv.w, wgtA[4 * j + 3], a0);
          a1 = fmaf(hv.x, wgtB[4 * j], a1);
          a1 = fmaf(hv.y, wgtB[4 * j + 1], a1);
          a1 = fmaf(hv.z, wgtB[4 * j + 2], a1);
          a1 = fmaf(hv.w, wgtB[4 * j + 3], a1);
        }
        bestA = fmaxf(bestA, a0);
        bestB = fmaxf(bestB, a1);
      }
      int s = s0 + g * 4 + w;
      out[24576 + b * 262144 + (co + lane) * 512 + s] = bestA + b2A;
      out[24576 + b * 262144 + (co + lane + 64) * 512 + s] = bestB + b2B;
      __syncthreads();
    }
  }
}

// ---------------------------------------------------------------------------
extern "C" void kernel_launch(void* const* d_in, const int* in_sizes, int n_in,
                              void* d_out, int out_size, void* d_ws, size_t ws_size,
                              hipStream_t stream) {
  const float* xyz = (const float*)d_in[0];    // l0_xyz  [B,3,N] f32
  const float* pts = (const float*)d_in[1];    // l0_points
  const float* sa_W1 = (const float*)d_in[2];  // [64,6]
  const float* sa_b1 = (const float*)d_in[3];  // [64]
  const float* sa_W2 = (const float*)d_in[4];  // [128,64]
  const float* sa_b2 = (const float*)d_in[5];  // [128]
  const float* ms_W1 = (const float*)d_in[6];  // [3,64,3]
  const float* ms_b1 = (const float*)d_in[7];  // [3,64]
  const float* ms_W2 = (const float*)d_in[8];  // [3,128,64]
  const float* ms_b2 = (const float*)d_in[9];  // [3,128]
  float* out = (float*)d_out;
  const float* kp = (const float*)d_out;  // keypoints written by FPS

  // workspace layout: knn u16[B*S*24] (393216 B) | xyz4 (2 MB) | pts4 (2 MB)
  // | progress u32[16]
  u16* knn = (u16*)d_ws;
  float4* xyz4 = (float4*)((char*)d_ws + 393216);
  float4* pts4 = xyz4 + BB * NN;
  u32* progress = (u32*)(pts4 + BB * NN);
  const size_t need = 393216 + (size_t)2 * BB * NN * sizeof(float4) + 64;
  const bool fused = ws_size >= need;

  if (fused) {
    k_prep<<<BB * NN / 256, 256, 0, stream>>>(xyz, pts, xyz4, pts4, progress);
    k_fps_knn<<<BB + KNN_BLOCKS, 512, 0, stream>>>(xyz, xyz4, out, knn, progress);
    k_mlp<1><<<dim3(BB * 64, 4), 256, 0, stream>>>(xyz, pts, xyz4, pts4, kp, knn,
                                                   sa_W1, sa_b1, sa_W2, sa_b2,
                                                   ms_W1, ms_b1, ms_W2, ms_b2, out);
  } else {
    k_fps_solo<<<BB, 512, 0, stream>>>(xyz, out);
    k_knn_solo<<<(BB * SS) / 4, 256, 0, stream>>>(xyz, kp, knn);
    k_mlp<0><<<dim3(BB * 64, 4), 256, 0, stream>>>(xyz, pts, xyz4, pts4, kp, knn,
                                                   sa_W1, sa_b1, sa_W2, sa_b2,
                                                   ms_W1, ms_b1, ms_W2, ms_b2, out);
  }
}